// Round 13
// baseline (543.625 us; speedup 1.0000x reference)
//
#include <hip/hip_runtime.h>
#include <hip/hip_bf16.h>

// GraphEncoder: 2-layer GATConv (edge_dim=4, heads=4, concat) on MI355X.
// N=50000, E=800000, IN=16, C1=64 (H*C1=256), C2=32 (H*C2=128).
//
// Key simplification: edge embeddings eh=ea@We only appear via dot with
// a_edge => precompute Ve[4x4] per layer, a_e = ea @ Ve. Never build eh.
//
// R1: agg cooperative (logits/exp once per edge-head in LDS) 322->189us.
// R4: hist float atomics removed; aeloop = segment-mean of ae (linearity).
// R5: bf16 gather tables; multi-block scan.
// R6: agg gather ushort2 + unroll x4 + CAP=96: agg1 171 -> <100us (off top-5).
// R12: gemm2 was LDS-issue-bound (1 uniform ds_read_b32 per FMA, VALUBusy 61%,
//     31TF=20% peak). Now 32x128 tile, 2 cols/thread, float4 LDS reads:
//     per k4-step 16 ds_read_b128 (192cy) vs 128 FMA (256cy) -> FMA-bound.

#define NEG_SLOPE 0.2f

__device__ __forceinline__ float lrelu(float v) { return v > 0.f ? v : NEG_SLOPE * v; }
__device__ __forceinline__ float bf_lo(unsigned v) { return __uint_as_float(v << 16); }
__device__ __forceinline__ float bf_hi(unsigned v) { return __uint_as_float(v & 0xffff0000u); }

// Ve1[d][h] = sum_c We1[d, h*64+c] * ae1[h,c];  Ve2 likewise with C=32.
__global__ void ve_kernel(const float* __restrict__ We1, const float* __restrict__ ae1,
                          const float* __restrict__ We2, const float* __restrict__ ae2,
                          float* __restrict__ Ve) {
    int t = threadIdx.x;
    if (t < 16) {
        int d = t >> 2, h = t & 3;
        float s = 0.f;
        for (int c = 0; c < 64; ++c) s += We1[d * 256 + h * 64 + c] * ae1[h * 64 + c];
        Ve[t] = s;
    } else if (t < 32) {
        int tt = t - 16;
        int d = tt >> 2, h = tt & 3;
        float s = 0.f;
        for (int c = 0; c < 32; ++c) s += We2[d * 128 + h * 32 + c] * ae2[h * 32 + c];
        Ve[16 + tt] = s;
    }
}

// in-degree histogram only.
__global__ void hist_kernel(const int* __restrict__ dst, int* __restrict__ cnt, int E) {
    int e = blockIdx.x * blockDim.x + threadIdx.x;
    if (e >= E) return;
    atomicAdd(&cnt[dst[e]], 1);
}

// ---- 3-phase multi-block exclusive scan of cnt -> off ----
__global__ void blockscan_kernel(const int* __restrict__ cnt, int* __restrict__ off,
                                 int* __restrict__ bsum, int n) {
    __shared__ int wsum[8];
    int b = blockIdx.x, tid = threadIdx.x;
    int i = b * 512 + tid;
    int lane = tid & 63, w = tid >> 6;
    int v = (i < n) ? cnt[i] : 0;
    int s = v;
#pragma unroll
    for (int o = 1; o < 64; o <<= 1) {
        int t = __shfl_up(s, o, 64);
        if (lane >= o) s += t;
    }
    if (lane == 63) wsum[w] = s;
    __syncthreads();
    if (tid == 0) {
        int run = 0;
#pragma unroll
        for (int k = 0; k < 8; ++k) { int t = wsum[k]; wsum[k] = run; run += t; }
        bsum[b] = run;
    }
    __syncthreads();
    s += wsum[w];
    if (i < n) off[i + 1] = s;  // block-local inclusive; bsum added in phase C
}

__global__ void bsumscan_kernel(int* __restrict__ bsum, int nb) {
    if (threadIdx.x == 0) {
        int run = 0;
        for (int k = 0; k < nb; ++k) { int t = bsum[k]; bsum[k] = run; run += t; }
    }
}

__global__ void scanadd_kernel(const int* __restrict__ bsum, int* __restrict__ off, int n) {
    int i = blockIdx.x * 512 + threadIdx.x;
    if (i == 0) off[0] = 0;
    if (i < n) off[i + 1] += bsum[blockIdx.x];
}

// counting-sort edges by dst; store src and per-layer a_e at sorted position.
__global__ void scatter_kernel(const int* __restrict__ src, const int* __restrict__ dst,
                               const float* __restrict__ ea, const int* __restrict__ off,
                               int* __restrict__ fill, const float* __restrict__ Ve,
                               int* __restrict__ src_sorted, float* __restrict__ ae1s,
                               float* __restrict__ ae2s, int E) {
    int e = blockIdx.x * blockDim.x + threadIdx.x;
    if (e >= E) return;
    int d = dst[e];
    int pos = off[d] + atomicAdd(&fill[d], 1);
    src_sorted[pos] = src[e];
    float e4[4];
#pragma unroll
    for (int k = 0; k < 4; ++k) e4[k] = ea[e * 4 + k];
#pragma unroll
    for (int h = 0; h < 4; ++h) {
        float s1 = 0.f, s2 = 0.f;
#pragma unroll
        for (int k = 0; k < 4; ++k) { s1 += e4[k] * Ve[k * 4 + h]; s2 += e4[k] * Ve[16 + k * 4 + h]; }
        ae1s[pos * 4 + h] = s1;
        ae2s[pos * 4 + h] = s2;
    }
}

// aeloopL[n][h] = mean over n's incoming edges of aeLs (linearity of @Ve).
__global__ void aeloop_kernel(const int* __restrict__ off,
                              const float* __restrict__ ae1s, const float* __restrict__ ae2s,
                              float* __restrict__ aeloop1, float* __restrict__ aeloop2, int n) {
    int t = blockIdx.x * blockDim.x + threadIdx.x;
    int node = t >> 3, k = t & 7;
    if (node >= n) return;
    int beg = off[node], end = off[node + 1];
    int deg = end - beg;
    float inv = 1.f / (float)(deg > 0 ? deg : 1);
    const float* srcp = (k < 4) ? ae1s : ae2s;
    int h = k & 3;
    float s = 0.f;
    for (int i = beg; i < end; ++i) s += srcp[(size_t)i * 4 + h];
    float* dstp = (k < 4) ? aeloop1 : aeloop2;
    dstp[(size_t)node * 4 + h] = s * inv;
}

// xh1 = x @ W1 ([N,16]@[16,256]) stored bf16; fused a_s1/a_d1 (f32 acc).
__global__ void gemm1_kernel(const float* __restrict__ x, const float* __restrict__ W1,
                             const float* __restrict__ as1, const float* __restrict__ ad1,
                             __hip_bfloat16* __restrict__ xh1, float* __restrict__ a_s,
                             float* __restrict__ a_d, int N) {
    constexpr int R = 8;
    __shared__ float sx[R * 16];
    int n0 = blockIdx.x * R;
    int j = threadIdx.x;
    for (int idx = j; idx < R * 16; idx += 256) {
        int r = idx >> 4, k = idx & 15;
        int nn = n0 + r;
        sx[idx] = (nn < N) ? x[nn * 16 + k] : 0.f;
    }
    __syncthreads();
    float acc[R];
#pragma unroll
    for (int r = 0; r < R; ++r) acc[r] = 0.f;
#pragma unroll
    for (int k = 0; k < 16; ++k) {
        float w = W1[k * 256 + j];
#pragma unroll
        for (int r = 0; r < R; ++r) acc[r] += sx[r * 16 + k] * w;
    }
    float as = as1[j], ad = ad1[j];
    int h = j >> 6;
#pragma unroll
    for (int r = 0; r < R; ++r) {
        int nn = n0 + r;
        if (nn < N) xh1[(size_t)nn * 256 + j] = __float2bfloat16(acc[r]);
        float va = acc[r] * as, vd = acc[r] * ad;
#pragma unroll
        for (int o = 32; o > 0; o >>= 1) {
            va += __shfl_xor(va, o, 64);
            vd += __shfl_xor(vd, o, 64);
        }
        if ((j & 63) == 0 && nn < N) { a_s[nn * 4 + h] = va; a_d[nn * 4 + h] = vd; }
    }
}

// xh2 = h1 @ W2 ([N,256]@[256,128]) stored bf16; fused a_s2/a_d2 (f32 acc).
// 32 rows x 128 cols per block, 128 threads. Thread t: cols (t&63, (t&63)+64),
// rows (t>>6)*16 .. +15. float4 LDS reads (ds_read_b128, wave-uniform bcast).
__global__ __launch_bounds__(128) void gemm2_kernel(
        const float* __restrict__ h1, const float* __restrict__ W2,
        const float* __restrict__ as2, const float* __restrict__ ad2,
        __hip_bfloat16* __restrict__ xh2, float* __restrict__ a_s,
        float* __restrict__ a_d, int N) {
    constexpr int R = 32;
    __shared__ float sh[R * 256];   // 32 KB
    int n0 = blockIdx.x * R;
    int t = threadIdx.x;
    int jc = t & 63;                // column base (cols jc and jc+64)
    int rg = t >> 6;                // row group: rows rg*16 .. rg*16+15
    // stage 32 rows x 256 cols, float4
    for (int idx = t; idx < R * 64; idx += 128) {
        int r = idx >> 6, k4 = idx & 63;
        int nn = n0 + r;
        float4 v = make_float4(0.f, 0.f, 0.f, 0.f);
        if (nn < N) v = *(const float4*)&h1[(size_t)nn * 256 + k4 * 4];
        *(float4*)&sh[r * 256 + k4 * 4] = v;
    }
    __syncthreads();
    float acc0[16], acc1[16];
#pragma unroll
    for (int r = 0; r < 16; ++r) { acc0[r] = 0.f; acc1[r] = 0.f; }
    const float* shb = &sh[rg * 16 * 256];
    for (int k4 = 0; k4 < 64; ++k4) {
        int k = k4 * 4;
        float w0a = W2[(k + 0) * 128 + jc], w0b = W2[(k + 0) * 128 + jc + 64];
        float w1a = W2[(k + 1) * 128 + jc], w1b = W2[(k + 1) * 128 + jc + 64];
        float w2a = W2[(k + 2) * 128 + jc], w2b = W2[(k + 2) * 128 + jc + 64];
        float w3a = W2[(k + 3) * 128 + jc], w3b = W2[(k + 3) * 128 + jc + 64];
#pragma unroll
        for (int r = 0; r < 16; ++r) {
            float4 s4 = *(const float4*)&shb[r * 256 + k];
            acc0[r] += s4.x * w0a + s4.y * w1a + s4.z * w2a + s4.w * w3a;
            acc1[r] += s4.x * w0b + s4.y * w1b + s4.z * w2b + s4.w * w3b;
        }
    }
    // epilogue: bf16 store + fused a_s2/a_d2 head reductions.
    // wave lanes 0..31 = cols 0..31 (head0 via acc0, head2 via acc1);
    // lanes 32..63 = cols 32..63 (head1 via acc0, head3 via acc1).
    float asa = as2[jc], asb = as2[jc + 64];
    float ada = ad2[jc], adb = ad2[jc + 64];
    int lane = t & 63;
#pragma unroll
    for (int r = 0; r < 16; ++r) {
        int nn = n0 + rg * 16 + r;
        if (nn < N) {
            xh2[(size_t)nn * 128 + jc]      = __float2bfloat16(acc0[r]);
            xh2[(size_t)nn * 128 + jc + 64] = __float2bfloat16(acc1[r]);
        }
        float vsa = acc0[r] * asa, vsb = acc1[r] * asb;
        float vda = acc0[r] * ada, vdb = acc1[r] * adb;
#pragma unroll
        for (int o = 16; o > 0; o >>= 1) {
            vsa += __shfl_xor(vsa, o, 32);
            vsb += __shfl_xor(vsb, o, 32);
            vda += __shfl_xor(vda, o, 32);
            vdb += __shfl_xor(vdb, o, 32);
        }
        if ((lane & 31) == 0 && nn < N) {
            int hbase = lane >> 5;  // 0 for lanes 0..31, 1 for 32..63
            a_s[(size_t)nn * 4 + hbase]     = vsa;
            a_s[(size_t)nn * 4 + 2 + hbase] = vsb;
            a_d[(size_t)nn * 4 + hbase]     = vda;
            a_d[(size_t)nn * 4 + 2 + hbase] = vdb;
        }
    }
}

// Per-node segment softmax + weighted gather-aggregate (cooperative).
// CT threads, CH channels, CPT = CH/CT channels per thread (1 or 2).
// Phase 3 gather: CPT==2 -> one 4B uint (2 bf16) per edge per thread;
// unrolled x4 for 4 loads in flight.
template <int CT, int CH>
__global__ __launch_bounds__(CT) void agg_kernel(
        const int* __restrict__ off, const int* __restrict__ srcs,
        const float* __restrict__ aes, const float* __restrict__ aeloop,
        const float* __restrict__ a_s, const float* __restrict__ a_d,
        const __hip_bfloat16* __restrict__ xh, const float* __restrict__ bias,
        float* __restrict__ out, int relu) {
    constexpr int CPT = CH / CT;    // channels per thread (1 or 2)
    constexpr int C   = CH / 4;     // channels per head
    constexpr int CAP = 96;         // max edges (incl. self) staged in LDS
    constexpr int NW  = CT / 64;    // waves per block
    constexpr int TPG = CT / 4;     // threads per head in phase 2
    __shared__ int   s_src[CAP];
    __shared__ float s_lg[CAP * 4];
    __shared__ float s_wred[NW * 4];
    __shared__ float s_m[4];
    __shared__ float s_den[4];

    int n = blockIdx.x;
    int j = threadIdx.x;
    int beg = off[n], end = off[n + 1];
    int deg = end - beg;
    int tot = deg + 1;  // + self loop
    int h = (j * CPT) / C;

    const float4 ad4 = *(const float4*)&a_d[(size_t)n * 4];

    if (tot <= CAP) {
        // ---- phase 1: logits, one edge per thread ----
        for (int idx = j; idx < tot; idx += CT) {
            int s; float4 ae;
            if (idx < deg) {
                s  = srcs[beg + idx];
                ae = *(const float4*)&aes[(size_t)(beg + idx) * 4];
            } else {
                s  = n;
                ae = *(const float4*)&aeloop[(size_t)n * 4];
            }
            s_src[idx] = s;
            float4 as4 = *(const float4*)&a_s[(size_t)s * 4];
            s_lg[idx * 4 + 0] = lrelu(as4.x + ad4.x + ae.x);
            s_lg[idx * 4 + 1] = lrelu(as4.y + ad4.y + ae.y);
            s_lg[idx * 4 + 2] = lrelu(as4.z + ad4.z + ae.z);
            s_lg[idx * 4 + 3] = lrelu(as4.w + ad4.w + ae.w);
        }
        __syncthreads();
        // ---- phase 2: per-head max, exp, denominator ----
        int lane = j & 63, w = j >> 6;
        int g = j & 3, r = j >> 2;
        float m = -3.4e38f;
        for (int i = r; i < tot; i += TPG) m = fmaxf(m, s_lg[i * 4 + g]);
#pragma unroll
        for (int o = 4; o < 64; o <<= 1) m = fmaxf(m, __shfl_xor(m, o, 64));
        if (lane < 4) s_wred[w * 4 + lane] = m;
        __syncthreads();
        if (j < 4) {
            float mm = s_wred[j];
            for (int ww = 1; ww < NW; ++ww) mm = fmaxf(mm, s_wred[ww * 4 + j]);
            s_m[j] = mm;
        }
        __syncthreads();
        float mh = s_m[g];
        float den = 0.f;
        for (int i = r; i < tot; i += TPG) {
            float e = expf(s_lg[i * 4 + g] - mh);
            s_lg[i * 4 + g] = e;
            den += e;
        }
#pragma unroll
        for (int o = 4; o < 64; o <<= 1) den += __shfl_xor(den, o, 64);
        if (lane < 4) s_wred[w * 4 + lane] = den;
        __syncthreads();
        if (j < 4) {
            float dd = s_wred[j];
            for (int ww = 1; ww < NW; ++ww) dd += s_wred[ww * 4 + j];
            s_den[j] = dd;
        }
        __syncthreads();
        // ---- phase 3: weighted gather (unroll x4, wide loads) ----
        float invden = 1.f / s_den[h];
        if constexpr (CPT == 2) {
            const unsigned* xu = (const unsigned*)xh;
            constexpr int CHW = CH / 2;
            float a0 = 0.f, a1 = 0.f;
            int i = 0;
            for (; i + 4 <= tot; i += 4) {
                float w0 = s_lg[(i+0)*4+h], w1 = s_lg[(i+1)*4+h];
                float w2 = s_lg[(i+2)*4+h], w3 = s_lg[(i+3)*4+h];
                int s0 = s_src[i+0], s1 = s_src[i+1], s2 = s_src[i+2], s3 = s_src[i+3];
                unsigned v0 = xu[(size_t)s0 * CHW + j];
                unsigned v1 = xu[(size_t)s1 * CHW + j];
                unsigned v2 = xu[(size_t)s2 * CHW + j];
                unsigned v3 = xu[(size_t)s3 * CHW + j];
                a0 += w0 * bf_lo(v0); a1 += w0 * bf_hi(v0);
                a0 += w1 * bf_lo(v1); a1 += w1 * bf_hi(v1);
                a0 += w2 * bf_lo(v2); a1 += w2 * bf_hi(v2);
                a0 += w3 * bf_lo(v3); a1 += w3 * bf_hi(v3);
            }
            for (; i < tot; ++i) {
                float ww = s_lg[i * 4 + h];
                unsigned v = xu[(size_t)s_src[i] * CHW + j];
                a0 += ww * bf_lo(v); a1 += ww * bf_hi(v);
            }
            float2 bb = ((const float2*)bias)[j];
            float o0 = a0 * invden + bb.x;
            float o1 = a1 * invden + bb.y;
            if (relu) { o0 = fmaxf(o0, 0.f); o1 = fmaxf(o1, 0.f); }
            ((float2*)&out[(size_t)n * CH])[j] = make_float2(o0, o1);
        } else {
            const unsigned short* xs = (const unsigned short*)xh;
            float a0 = 0.f;
            int i = 0;
            for (; i + 4 <= tot; i += 4) {
                float w0 = s_lg[(i+0)*4+h], w1 = s_lg[(i+1)*4+h];
                float w2 = s_lg[(i+2)*4+h], w3 = s_lg[(i+3)*4+h];
                int s0 = s_src[i+0], s1 = s_src[i+1], s2 = s_src[i+2], s3 = s_src[i+3];
                float x0 = __uint_as_float((unsigned)xs[(size_t)s0 * CH + j] << 16);
                float x1 = __uint_as_float((unsigned)xs[(size_t)s1 * CH + j] << 16);
                float x2 = __uint_as_float((unsigned)xs[(size_t)s2 * CH + j] << 16);
                float x3 = __uint_as_float((unsigned)xs[(size_t)s3 * CH + j] << 16);
                a0 += w0 * x0; a0 += w1 * x1; a0 += w2 * x2; a0 += w3 * x3;
            }
            for (; i < tot; ++i)
                a0 += s_lg[i * 4 + h] *
                      __uint_as_float((unsigned)xs[(size_t)s_src[i] * CH + j] << 16);
            float o2 = a0 * invden + bias[j];
            if (relu) o2 = fmaxf(o2, 0.f);
            out[(size_t)n * CH + j] = o2;
        }
    } else {
        // ---- fallback (deg+1 > CAP): per-thread two-pass (correct, slow) ----
        for (int c = j * CPT; c < (j + 1) * CPT; ++c) {
            int hh = c / C;
            float adh = ((const float*)&ad4)[hh];
            float lself = lrelu(a_s[(size_t)n * 4 + hh] + adh + aeloop[(size_t)n * 4 + hh]);
            float m = lself;
            for (int i2 = beg; i2 < end; ++i2) {
                int s = srcs[i2];
                float lg = lrelu(a_s[(size_t)s * 4 + hh] + adh + aes[(size_t)i2 * 4 + hh]);
                m = fmaxf(m, lg);
            }
            float ex = expf(lself - m);
            float den = ex;
            float acc = ex * __bfloat162float(xh[(size_t)n * CH + c]);
            for (int i2 = beg; i2 < end; ++i2) {
                int s = srcs[i2];
                float lg = lrelu(a_s[(size_t)s * 4 + hh] + adh + aes[(size_t)i2 * 4 + hh]);
                float e2 = expf(lg - m);
                den += e2;
                acc += e2 * __bfloat162float(xh[(size_t)s * CH + c]);
            }
            float o2 = acc / den + bias[c];
            if (relu) o2 = fmaxf(o2, 0.f);
            out[(size_t)n * CH + c] = o2;
        }
    }
}

extern "C" void kernel_launch(void* const* d_in, const int* in_sizes, int n_in,
                              void* d_out, int out_size, void* d_ws, size_t ws_size,
                              hipStream_t stream) {
    const float* x   = (const float*)d_in[0];
    const int*   ei  = (const int*)d_in[1];
    const float* ea  = (const float*)d_in[2];
    const float* W1  = (const float*)d_in[3];
    const float* We1 = (const float*)d_in[4];
    const float* as1 = (const float*)d_in[5];
    const float* ad1 = (const float*)d_in[6];
    const float* ae1 = (const float*)d_in[7];
    const float* b1  = (const float*)d_in[8];
    const float* W2  = (const float*)d_in[9];
    const float* We2 = (const float*)d_in[10];
    const float* as2 = (const float*)d_in[11];
    const float* ad2 = (const float*)d_in[12];
    const float* ae2 = (const float*)d_in[13];
    const float* b2  = (const float*)d_in[14];
    float* out = (float*)d_out;

    const int N = in_sizes[0] / 16;
    const int E = in_sizes[1] / 2;
    const int* srcp = ei;
    const int* dstp = ei + E;
    const int NB = (N + 511) / 512;

    char* w = (char*)d_ws;
    size_t o = 0;
    auto alloc = [&](size_t bytes) -> void* {
        void* p = w + o;
        o += (bytes + 255) & ~(size_t)255;
        return p;
    };
    // zeroed prefix: cnt | fill (one memset covers both)
    int*   cnt     = (int*)alloc((size_t)N * 4);
    int*   fill    = (int*)alloc((size_t)N * 4);
    size_t zero_bytes = o;
    int*   off_    = (int*)alloc((size_t)(N + 1) * 4);
    int*   bsum    = (int*)alloc((size_t)NB * 4);
    float* Ve      = (float*)alloc(32 * 4);
    float* aeloop1 = (float*)alloc((size_t)N * 16);
    float* aeloop2 = (float*)alloc((size_t)N * 16);
    float* a_s1    = (float*)alloc((size_t)N * 16);
    float* a_d1    = (float*)alloc((size_t)N * 16);
    float* a_s2    = (float*)alloc((size_t)N * 16);
    float* a_d2    = (float*)alloc((size_t)N * 16);
    int*   src_s   = (int*)alloc((size_t)E * 4);
    float* ae1s    = (float*)alloc((size_t)E * 16);
    float* ae2s    = (float*)alloc((size_t)E * 16);
    __hip_bfloat16* xh1 = (__hip_bfloat16*)alloc((size_t)N * 256 * 2);
    float* h1      = (float*)alloc((size_t)N * 256 * 4);
    __hip_bfloat16* xh2 = xh1;  // xh1 dead after agg1; reuse ([N,128] bf16 fits)

    hipMemsetAsync(d_ws, 0, zero_bytes, stream);
    ve_kernel<<<1, 64, 0, stream>>>(We1, ae1, We2, ae2, Ve);
    hist_kernel<<<(E + 255) / 256, 256, 0, stream>>>(dstp, cnt, E);
    blockscan_kernel<<<NB, 512, 0, stream>>>(cnt, off_, bsum, N);
    bsumscan_kernel<<<1, 64, 0, stream>>>(bsum, NB);
    scanadd_kernel<<<NB, 512, 0, stream>>>(bsum, off_, N);
    scatter_kernel<<<(E + 255) / 256, 256, 0, stream>>>(srcp, dstp, ea, off_, fill, Ve,
                                                        src_s, ae1s, ae2s, E);
    aeloop_kernel<<<(N * 8 + 255) / 256, 256, 0, stream>>>(off_, ae1s, ae2s,
                                                           aeloop1, aeloop2, N);
    // layer 1
    gemm1_kernel<<<(N + 7) / 8, 256, 0, stream>>>(x, W1, as1, ad1, xh1, a_s1, a_d1, N);
    agg_kernel<128, 256><<<N, 128, 0, stream>>>(off_, src_s, ae1s, aeloop1, a_s1, a_d1,
                                                xh1, b1, h1, 1);
    // layer 2
    gemm2_kernel<<<(N + 31) / 32, 128, 0, stream>>>(h1, W2, as2, ad2, xh2, a_s2, a_d2, N);
    agg_kernel<128, 128><<<N, 128, 0, stream>>>(off_, src_s, ae2s, aeloop2, a_s2, a_d2,
                                                xh2, b2, out, 0);
}

// Round 17
// 536.746 us; speedup vs baseline: 1.0128x; 1.0128x over previous
//
#include <hip/hip_runtime.h>
#include <hip/hip_bf16.h>

// GraphEncoder: 2-layer GATConv (edge_dim=4, heads=4, concat) on MI355X.
// N=50000, E=800000, IN=16, C1=64 (H*C1=256), C2=32 (H*C2=128).
//
// Key simplification: edge embeddings eh=ea@We only appear via dot with
// a_edge => precompute Ve[4x4] per layer, a_e = ea @ Ve. Never build eh.
//
// R1: agg cooperative (logits/exp once per edge-head in LDS) 322->189us.
// R4: hist float atomics removed; aeloop = segment-mean of ae (linearity).
// R5: bf16 gather tables; multi-block scan.
// R6: agg gather ushort2 + unroll x4 + CAP=96: agg1 171 -> <100us (off top-5).
// R12: gemm2 32x128/2-wave/32KB-LDS: REGRESSED 105->127us (occupancy 35->14.5%,
//      VALUBusy 41% — global-latency-bound with ~2 blocks/CU).
// R13: same 2-col/thread math (epilogue validated), but 256 thr / R=16 /
//      16KB LDS / acc=8: 4 b128 LDS (48cy) vs 32 FMA (64cy) per k4, with
//      ~8 blocks/CU to hide W2 L2 latency.
// R14-R16: infra timeouts — resubmitting R13 source unchanged for measurement.

#define NEG_SLOPE 0.2f

__device__ __forceinline__ float lrelu(float v) { return v > 0.f ? v : NEG_SLOPE * v; }
__device__ __forceinline__ float bf_lo(unsigned v) { return __uint_as_float(v << 16); }
__device__ __forceinline__ float bf_hi(unsigned v) { return __uint_as_float(v & 0xffff0000u); }

// Ve1[d][h] = sum_c We1[d, h*64+c] * ae1[h,c];  Ve2 likewise with C=32.
__global__ void ve_kernel(const float* __restrict__ We1, const float* __restrict__ ae1,
                          const float* __restrict__ We2, const float* __restrict__ ae2,
                          float* __restrict__ Ve) {
    int t = threadIdx.x;
    if (t < 16) {
        int d = t >> 2, h = t & 3;
        float s = 0.f;
        for (int c = 0; c < 64; ++c) s += We1[d * 256 + h * 64 + c] * ae1[h * 64 + c];
        Ve[t] = s;
    } else if (t < 32) {
        int tt = t - 16;
        int d = tt >> 2, h = tt & 3;
        float s = 0.f;
        for (int c = 0; c < 32; ++c) s += We2[d * 128 + h * 32 + c] * ae2[h * 32 + c];
        Ve[16 + tt] = s;
    }
}

// in-degree histogram only.
__global__ void hist_kernel(const int* __restrict__ dst, int* __restrict__ cnt, int E) {
    int e = blockIdx.x * blockDim.x + threadIdx.x;
    if (e >= E) return;
    atomicAdd(&cnt[dst[e]], 1);
}

// ---- 3-phase multi-block exclusive scan of cnt -> off ----
__global__ void blockscan_kernel(const int* __restrict__ cnt, int* __restrict__ off,
                                 int* __restrict__ bsum, int n) {
    __shared__ int wsum[8];
    int b = blockIdx.x, tid = threadIdx.x;
    int i = b * 512 + tid;
    int lane = tid & 63, w = tid >> 6;
    int v = (i < n) ? cnt[i] : 0;
    int s = v;
#pragma unroll
    for (int o = 1; o < 64; o <<= 1) {
        int t = __shfl_up(s, o, 64);
        if (lane >= o) s += t;
    }
    if (lane == 63) wsum[w] = s;
    __syncthreads();
    if (tid == 0) {
        int run = 0;
#pragma unroll
        for (int k = 0; k < 8; ++k) { int t = wsum[k]; wsum[k] = run; run += t; }
        bsum[b] = run;
    }
    __syncthreads();
    s += wsum[w];
    if (i < n) off[i + 1] = s;  // block-local inclusive; bsum added in phase C
}

__global__ void bsumscan_kernel(int* __restrict__ bsum, int nb) {
    if (threadIdx.x == 0) {
        int run = 0;
        for (int k = 0; k < nb; ++k) { int t = bsum[k]; bsum[k] = run; run += t; }
    }
}

__global__ void scanadd_kernel(const int* __restrict__ bsum, int* __restrict__ off, int n) {
    int i = blockIdx.x * 512 + threadIdx.x;
    if (i == 0) off[0] = 0;
    if (i < n) off[i + 1] += bsum[blockIdx.x];
}

// counting-sort edges by dst; store src and per-layer a_e at sorted position.
__global__ void scatter_kernel(const int* __restrict__ src, const int* __restrict__ dst,
                               const float* __restrict__ ea, const int* __restrict__ off,
                               int* __restrict__ fill, const float* __restrict__ Ve,
                               int* __restrict__ src_sorted, float* __restrict__ ae1s,
                               float* __restrict__ ae2s, int E) {
    int e = blockIdx.x * blockDim.x + threadIdx.x;
    if (e >= E) return;
    int d = dst[e];
    int pos = off[d] + atomicAdd(&fill[d], 1);
    src_sorted[pos] = src[e];
    float e4[4];
#pragma unroll
    for (int k = 0; k < 4; ++k) e4[k] = ea[e * 4 + k];
#pragma unroll
    for (int h = 0; h < 4; ++h) {
        float s1 = 0.f, s2 = 0.f;
#pragma unroll
        for (int k = 0; k < 4; ++k) { s1 += e4[k] * Ve[k * 4 + h]; s2 += e4[k] * Ve[16 + k * 4 + h]; }
        ae1s[pos * 4 + h] = s1;
        ae2s[pos * 4 + h] = s2;
    }
}

// aeloopL[n][h] = mean over n's incoming edges of aeLs (linearity of @Ve).
__global__ void aeloop_kernel(const int* __restrict__ off,
                              const float* __restrict__ ae1s, const float* __restrict__ ae2s,
                              float* __restrict__ aeloop1, float* __restrict__ aeloop2, int n) {
    int t = blockIdx.x * blockDim.x + threadIdx.x;
    int node = t >> 3, k = t & 7;
    if (node >= n) return;
    int beg = off[node], end = off[node + 1];
    int deg = end - beg;
    float inv = 1.f / (float)(deg > 0 ? deg : 1);
    const float* srcp = (k < 4) ? ae1s : ae2s;
    int h = k & 3;
    float s = 0.f;
    for (int i = beg; i < end; ++i) s += srcp[(size_t)i * 4 + h];
    float* dstp = (k < 4) ? aeloop1 : aeloop2;
    dstp[(size_t)node * 4 + h] = s * inv;
}

// xh1 = x @ W1 ([N,16]@[16,256]) stored bf16; fused a_s1/a_d1 (f32 acc).
__global__ void gemm1_kernel(const float* __restrict__ x, const float* __restrict__ W1,
                             const float* __restrict__ as1, const float* __restrict__ ad1,
                             __hip_bfloat16* __restrict__ xh1, float* __restrict__ a_s,
                             float* __restrict__ a_d, int N) {
    constexpr int R = 8;
    __shared__ float sx[R * 16];
    int n0 = blockIdx.x * R;
    int j = threadIdx.x;
    for (int idx = j; idx < R * 16; idx += 256) {
        int r = idx >> 4, k = idx & 15;
        int nn = n0 + r;
        sx[idx] = (nn < N) ? x[nn * 16 + k] : 0.f;
    }
    __syncthreads();
    float acc[R];
#pragma unroll
    for (int r = 0; r < R; ++r) acc[r] = 0.f;
#pragma unroll
    for (int k = 0; k < 16; ++k) {
        float w = W1[k * 256 + j];
#pragma unroll
        for (int r = 0; r < R; ++r) acc[r] += sx[r * 16 + k] * w;
    }
    float as = as1[j], ad = ad1[j];
    int h = j >> 6;
#pragma unroll
    for (int r = 0; r < R; ++r) {
        int nn = n0 + r;
        if (nn < N) xh1[(size_t)nn * 256 + j] = __float2bfloat16(acc[r]);
        float va = acc[r] * as, vd = acc[r] * ad;
#pragma unroll
        for (int o = 32; o > 0; o >>= 1) {
            va += __shfl_xor(va, o, 64);
            vd += __shfl_xor(vd, o, 64);
        }
        if ((j & 63) == 0 && nn < N) { a_s[nn * 4 + h] = va; a_d[nn * 4 + h] = vd; }
    }
}

// xh2 = h1 @ W2 ([N,256]@[256,128]) stored bf16; fused a_s2/a_d2 (f32 acc).
// 16 rows x 128 cols per block, 256 threads (4 row-groups x 4 rows).
// Thread t: cols (t&63, (t&63)+64), rows (t>>6)*4 .. +3. float4 LDS reads.
__global__ __launch_bounds__(256) void gemm2_kernel(
        const float* __restrict__ h1, const float* __restrict__ W2,
        const float* __restrict__ as2, const float* __restrict__ ad2,
        __hip_bfloat16* __restrict__ xh2, float* __restrict__ a_s,
        float* __restrict__ a_d, int N) {
    constexpr int R = 16;
    __shared__ float sh[R * 256];   // 16 KB
    int n0 = blockIdx.x * R;
    int t = threadIdx.x;
    int jc = t & 63;                // column base (cols jc and jc+64)
    int rg = t >> 6;                // row group: rows rg*4 .. rg*4+3
    // stage 16 rows x 256 cols, float4
    for (int idx = t; idx < R * 64; idx += 256) {
        int r = idx >> 6, k4 = idx & 63;
        int nn = n0 + r;
        float4 v = make_float4(0.f, 0.f, 0.f, 0.f);
        if (nn < N) v = *(const float4*)&h1[(size_t)nn * 256 + k4 * 4];
        *(float4*)&sh[r * 256 + k4 * 4] = v;
    }
    __syncthreads();
    float acc0[4], acc1[4];
#pragma unroll
    for (int r = 0; r < 4; ++r) { acc0[r] = 0.f; acc1[r] = 0.f; }
    const float* shb = &sh[rg * 4 * 256];
    for (int k4 = 0; k4 < 64; ++k4) {
        int k = k4 * 4;
        float w0a = W2[(k + 0) * 128 + jc], w0b = W2[(k + 0) * 128 + jc + 64];
        float w1a = W2[(k + 1) * 128 + jc], w1b = W2[(k + 1) * 128 + jc + 64];
        float w2a = W2[(k + 2) * 128 + jc], w2b = W2[(k + 2) * 128 + jc + 64];
        float w3a = W2[(k + 3) * 128 + jc], w3b = W2[(k + 3) * 128 + jc + 64];
#pragma unroll
        for (int r = 0; r < 4; ++r) {
            float4 s4 = *(const float4*)&shb[r * 256 + k];
            acc0[r] += s4.x * w0a + s4.y * w1a + s4.z * w2a + s4.w * w3a;
            acc1[r] += s4.x * w0b + s4.y * w1b + s4.z * w2b + s4.w * w3b;
        }
    }
    // epilogue: bf16 store + fused a_s2/a_d2 head reductions.
    // wave lanes 0..31 = cols 0..31 (head0 via acc0, head2 via acc1);
    // lanes 32..63 = cols 32..63 (head1 via acc0, head3 via acc1).
    float asa = as2[jc], asb = as2[jc + 64];
    float ada = ad2[jc], adb = ad2[jc + 64];
    int lane = t & 63;
#pragma unroll
    for (int r = 0; r < 4; ++r) {
        int nn = n0 + rg * 4 + r;
        if (nn < N) {
            xh2[(size_t)nn * 128 + jc]      = __float2bfloat16(acc0[r]);
            xh2[(size_t)nn * 128 + jc + 64] = __float2bfloat16(acc1[r]);
        }
        float vsa = acc0[r] * asa, vsb = acc1[r] * asb;
        float vda = acc0[r] * ada, vdb = acc1[r] * adb;
#pragma unroll
        for (int o = 16; o > 0; o >>= 1) {
            vsa += __shfl_xor(vsa, o, 32);
            vsb += __shfl_xor(vsb, o, 32);
            vda += __shfl_xor(vda, o, 32);
            vdb += __shfl_xor(vdb, o, 32);
        }
        if ((lane & 31) == 0 && nn < N) {
            int hbase = lane >> 5;  // 0 for lanes 0..31, 1 for 32..63
            a_s[(size_t)nn * 4 + hbase]     = vsa;
            a_s[(size_t)nn * 4 + 2 + hbase] = vsb;
            a_d[(size_t)nn * 4 + hbase]     = vda;
            a_d[(size_t)nn * 4 + 2 + hbase] = vdb;
        }
    }
}

// Per-node segment softmax + weighted gather-aggregate (cooperative).
// CT threads, CH channels, CPT = CH/CT channels per thread (1 or 2).
// Phase 3 gather: CPT==2 -> one 4B uint (2 bf16) per edge per thread;
// unrolled x4 for 4 loads in flight.
template <int CT, int CH>
__global__ __launch_bounds__(CT) void agg_kernel(
        const int* __restrict__ off, const int* __restrict__ srcs,
        const float* __restrict__ aes, const float* __restrict__ aeloop,
        const float* __restrict__ a_s, const float* __restrict__ a_d,
        const __hip_bfloat16* __restrict__ xh, const float* __restrict__ bias,
        float* __restrict__ out, int relu) {
    constexpr int CPT = CH / CT;    // channels per thread (1 or 2)
    constexpr int C   = CH / 4;     // channels per head
    constexpr int CAP = 96;         // max edges (incl. self) staged in LDS
    constexpr int NW  = CT / 64;    // waves per block
    constexpr int TPG = CT / 4;     // threads per head in phase 2
    __shared__ int   s_src[CAP];
    __shared__ float s_lg[CAP * 4];
    __shared__ float s_wred[NW * 4];
    __shared__ float s_m[4];
    __shared__ float s_den[4];

    int n = blockIdx.x;
    int j = threadIdx.x;
    int beg = off[n], end = off[n + 1];
    int deg = end - beg;
    int tot = deg + 1;  // + self loop
    int h = (j * CPT) / C;

    const float4 ad4 = *(const float4*)&a_d[(size_t)n * 4];

    if (tot <= CAP) {
        // ---- phase 1: logits, one edge per thread ----
        for (int idx = j; idx < tot; idx += CT) {
            int s; float4 ae;
            if (idx < deg) {
                s  = srcs[beg + idx];
                ae = *(const float4*)&aes[(size_t)(beg + idx) * 4];
            } else {
                s  = n;
                ae = *(const float4*)&aeloop[(size_t)n * 4];
            }
            s_src[idx] = s;
            float4 as4 = *(const float4*)&a_s[(size_t)s * 4];
            s_lg[idx * 4 + 0] = lrelu(as4.x + ad4.x + ae.x);
            s_lg[idx * 4 + 1] = lrelu(as4.y + ad4.y + ae.y);
            s_lg[idx * 4 + 2] = lrelu(as4.z + ad4.z + ae.z);
            s_lg[idx * 4 + 3] = lrelu(as4.w + ad4.w + ae.w);
        }
        __syncthreads();
        // ---- phase 2: per-head max, exp, denominator ----
        int lane = j & 63, w = j >> 6;
        int g = j & 3, r = j >> 2;
        float m = -3.4e38f;
        for (int i = r; i < tot; i += TPG) m = fmaxf(m, s_lg[i * 4 + g]);
#pragma unroll
        for (int o = 4; o < 64; o <<= 1) m = fmaxf(m, __shfl_xor(m, o, 64));
        if (lane < 4) s_wred[w * 4 + lane] = m;
        __syncthreads();
        if (j < 4) {
            float mm = s_wred[j];
            for (int ww = 1; ww < NW; ++ww) mm = fmaxf(mm, s_wred[ww * 4 + j]);
            s_m[j] = mm;
        }
        __syncthreads();
        float mh = s_m[g];
        float den = 0.f;
        for (int i = r; i < tot; i += TPG) {
            float e = expf(s_lg[i * 4 + g] - mh);
            s_lg[i * 4 + g] = e;
            den += e;
        }
#pragma unroll
        for (int o = 4; o < 64; o <<= 1) den += __shfl_xor(den, o, 64);
        if (lane < 4) s_wred[w * 4 + lane] = den;
        __syncthreads();
        if (j < 4) {
            float dd = s_wred[j];
            for (int ww = 1; ww < NW; ++ww) dd += s_wred[ww * 4 + j];
            s_den[j] = dd;
        }
        __syncthreads();
        // ---- phase 3: weighted gather (unroll x4, wide loads) ----
        float invden = 1.f / s_den[h];
        if constexpr (CPT == 2) {
            const unsigned* xu = (const unsigned*)xh;
            constexpr int CHW = CH / 2;
            float a0 = 0.f, a1 = 0.f;
            int i = 0;
            for (; i + 4 <= tot; i += 4) {
                float w0 = s_lg[(i+0)*4+h], w1 = s_lg[(i+1)*4+h];
                float w2 = s_lg[(i+2)*4+h], w3 = s_lg[(i+3)*4+h];
                int s0 = s_src[i+0], s1 = s_src[i+1], s2 = s_src[i+2], s3 = s_src[i+3];
                unsigned v0 = xu[(size_t)s0 * CHW + j];
                unsigned v1 = xu[(size_t)s1 * CHW + j];
                unsigned v2 = xu[(size_t)s2 * CHW + j];
                unsigned v3 = xu[(size_t)s3 * CHW + j];
                a0 += w0 * bf_lo(v0); a1 += w0 * bf_hi(v0);
                a0 += w1 * bf_lo(v1); a1 += w1 * bf_hi(v1);
                a0 += w2 * bf_lo(v2); a1 += w2 * bf_hi(v2);
                a0 += w3 * bf_lo(v3); a1 += w3 * bf_hi(v3);
            }
            for (; i < tot; ++i) {
                float ww = s_lg[i * 4 + h];
                unsigned v = xu[(size_t)s_src[i] * CHW + j];
                a0 += ww * bf_lo(v); a1 += ww * bf_hi(v);
            }
            float2 bb = ((const float2*)bias)[j];
            float o0 = a0 * invden + bb.x;
            float o1 = a1 * invden + bb.y;
            if (relu) { o0 = fmaxf(o0, 0.f); o1 = fmaxf(o1, 0.f); }
            ((float2*)&out[(size_t)n * CH])[j] = make_float2(o0, o1);
        } else {
            const unsigned short* xs = (const unsigned short*)xh;
            float a0 = 0.f;
            int i = 0;
            for (; i + 4 <= tot; i += 4) {
                float w0 = s_lg[(i+0)*4+h], w1 = s_lg[(i+1)*4+h];
                float w2 = s_lg[(i+2)*4+h], w3 = s_lg[(i+3)*4+h];
                int s0 = s_src[i+0], s1 = s_src[i+1], s2 = s_src[i+2], s3 = s_src[i+3];
                float x0 = __uint_as_float((unsigned)xs[(size_t)s0 * CH + j] << 16);
                float x1 = __uint_as_float((unsigned)xs[(size_t)s1 * CH + j] << 16);
                float x2 = __uint_as_float((unsigned)xs[(size_t)s2 * CH + j] << 16);
                float x3 = __uint_as_float((unsigned)xs[(size_t)s3 * CH + j] << 16);
                a0 += w0 * x0; a0 += w1 * x1; a0 += w2 * x2; a0 += w3 * x3;
            }
            for (; i < tot; ++i)
                a0 += s_lg[i * 4 + h] *
                      __uint_as_float((unsigned)xs[(size_t)s_src[i] * CH + j] << 16);
            float o2 = a0 * invden + bias[j];
            if (relu) o2 = fmaxf(o2, 0.f);
            out[(size_t)n * CH + j] = o2;
        }
    } else {
        // ---- fallback (deg+1 > CAP): per-thread two-pass (correct, slow) ----
        for (int c = j * CPT; c < (j + 1) * CPT; ++c) {
            int hh = c / C;
            float adh = ((const float*)&ad4)[hh];
            float lself = lrelu(a_s[(size_t)n * 4 + hh] + adh + aeloop[(size_t)n * 4 + hh]);
            float m = lself;
            for (int i2 = beg; i2 < end; ++i2) {
                int s = srcs[i2];
                float lg = lrelu(a_s[(size_t)s * 4 + hh] + adh + aes[(size_t)i2 * 4 + hh]);
                m = fmaxf(m, lg);
            }
            float ex = expf(lself - m);
            float den = ex;
            float acc = ex * __bfloat162float(xh[(size_t)n * CH + c]);
            for (int i2 = beg; i2 < end; ++i2) {
                int s = srcs[i2];
                float lg = lrelu(a_s[(size_t)s * 4 + hh] + adh + aes[(size_t)i2 * 4 + hh]);
                float e2 = expf(lg - m);
                den += e2;
                acc += e2 * __bfloat162float(xh[(size_t)s * CH + c]);
            }
            float o2 = acc / den + bias[c];
            if (relu) o2 = fmaxf(o2, 0.f);
            out[(size_t)n * CH + c] = o2;
        }
    }
}

extern "C" void kernel_launch(void* const* d_in, const int* in_sizes, int n_in,
                              void* d_out, int out_size, void* d_ws, size_t ws_size,
                              hipStream_t stream) {
    const float* x   = (const float*)d_in[0];
    const int*   ei  = (const int*)d_in[1];
    const float* ea  = (const float*)d_in[2];
    const float* W1  = (const float*)d_in[3];
    const float* We1 = (const float*)d_in[4];
    const float* as1 = (const float*)d_in[5];
    const float* ad1 = (const float*)d_in[6];
    const float* ae1 = (const float*)d_in[7];
    const float* b1  = (const float*)d_in[8];
    const float* W2  = (const float*)d_in[9];
    const float* We2 = (const float*)d_in[10];
    const float* as2 = (const float*)d_in[11];
    const float* ad2 = (const float*)d_in[12];
    const float* ae2 = (const float*)d_in[13];
    const float* b2  = (const float*)d_in[14];
    float* out = (float*)d_out;

    const int N = in_sizes[0] / 16;
    const int E = in_sizes[1] / 2;
    const int* srcp = ei;
    const int* dstp = ei + E;
    const int NB = (N + 511) / 512;

    char* w = (char*)d_ws;
    size_t o = 0;
    auto alloc = [&](size_t bytes) -> void* {
        void* p = w + o;
        o += (bytes + 255) & ~(size_t)255;
        return p;
    };
    // zeroed prefix: cnt | fill (one memset covers both)
    int*   cnt     = (int*)alloc((size_t)N * 4);
    int*   fill    = (int*)alloc((size_t)N * 4);
    size_t zero_bytes = o;
    int*   off_    = (int*)alloc((size_t)(N + 1) * 4);
    int*   bsum    = (int*)alloc((size_t)NB * 4);
    float* Ve      = (float*)alloc(32 * 4);
    float* aeloop1 = (float*)alloc((size_t)N * 16);
    float* aeloop2 = (float*)alloc((size_t)N * 16);
    float* a_s1    = (float*)alloc((size_t)N * 16);
    float* a_d1    = (float*)alloc((size_t)N * 16);
    float* a_s2    = (float*)alloc((size_t)N * 16);
    float* a_d2    = (float*)alloc((size_t)N * 16);
    int*   src_s   = (int*)alloc((size_t)E * 4);
    float* ae1s    = (float*)alloc((size_t)E * 16);
    float* ae2s    = (float*)alloc((size_t)E * 16);
    __hip_bfloat16* xh1 = (__hip_bfloat16*)alloc((size_t)N * 256 * 2);
    float* h1      = (float*)alloc((size_t)N * 256 * 4);
    __hip_bfloat16* xh2 = xh1;  // xh1 dead after agg1; reuse ([N,128] bf16 fits)

    hipMemsetAsync(d_ws, 0, zero_bytes, stream);
    ve_kernel<<<1, 64, 0, stream>>>(We1, ae1, We2, ae2, Ve);
    hist_kernel<<<(E + 255) / 256, 256, 0, stream>>>(dstp, cnt, E);
    blockscan_kernel<<<NB, 512, 0, stream>>>(cnt, off_, bsum, N);
    bsumscan_kernel<<<1, 64, 0, stream>>>(bsum, NB);
    scanadd_kernel<<<NB, 512, 0, stream>>>(bsum, off_, N);
    scatter_kernel<<<(E + 255) / 256, 256, 0, stream>>>(srcp, dstp, ea, off_, fill, Ve,
                                                        src_s, ae1s, ae2s, E);
    aeloop_kernel<<<(N * 8 + 255) / 256, 256, 0, stream>>>(off_, ae1s, ae2s,
                                                           aeloop1, aeloop2, N);
    // layer 1
    gemm1_kernel<<<(N + 7) / 8, 256, 0, stream>>>(x, W1, as1, ad1, xh1, a_s1, a_d1, N);
    agg_kernel<128, 256><<<N, 128, 0, stream>>>(off_, src_s, ae1s, aeloop1, a_s1, a_d1,
                                                xh1, b1, h1, 1);
    // layer 2
    gemm2_kernel<<<(N + 15) / 16, 256, 0, stream>>>(h1, W2, as2, ad2, xh2, a_s2, a_d2, N);
    agg_kernel<128, 128><<<N, 128, 0, stream>>>(off_, src_s, ae2s, aeloop2, a_s2, a_d2,
                                                xh2, b2, out, 0);
}